// Round 1
// baseline (175.874 us; speedup 1.0000x reference)
//
#include <hip/hip_runtime.h>
#include <hip/hip_bf16.h>

#define N_NODES 100000
#define DEG 16
#define C 128            // C_IN == C_OUT == 128
#define LDS_STRIDE 136   // 128 + 8 pad (keeps 16B alignment, breaks bank conflicts)

typedef __attribute__((ext_vector_type(8))) short short8;
typedef __attribute__((ext_vector_type(4))) float f32x4;

// fp32 -> bf16 bits, round-to-nearest-even (matches numpy)
__device__ inline unsigned short f2bf(float f) {
    unsigned int u = __builtin_bit_cast(unsigned int, f);
    u += 0x7fffu + ((u >> 16) & 1u);
    return (unsigned short)(u >> 16);
}
__device__ inline float bflo(unsigned int p) { return __builtin_bit_cast(float, p << 16); }
__device__ inline float bfhi(unsigned int p) { return __builtin_bit_cast(float, p & 0xffff0000u); }

// ---------------------------------------------------------------------------
// Kernel 1: h[m][n] = (sum_k x[m][k] * W[k][n]) * out_norm[m], stored as bf16.
// One wave computes a 16-row x 128-col tile via 8 column-tiles of 16x16x(4*32).
// W is staged transposed (Wt[n][k]) in LDS as bf16.
// ---------------------------------------------------------------------------
__global__ __launch_bounds__(256, 4)
void gcn_gemm_kernel(const float* __restrict__ x, const float* __restrict__ w,
                     const int* __restrict__ colptr, unsigned short* __restrict__ h)
{
    __shared__ unsigned short wt[C * LDS_STRIDE];   // ~34.8 KB

    int tid = threadIdx.x;
    // Load + transpose W (row-major [k][n] fp32) into LDS as Wt[n][k] bf16.
    for (int i = tid; i < C * C; i += 256) {
        int k = i >> 7;
        int n = i & 127;
        wt[n * LDS_STRIDE + k] = f2bf(w[i]);
    }
    __syncthreads();

    int wave = tid >> 6;
    int lane = tid & 63;
    int tile = blockIdx.x * 4 + wave;    // 16-row tile index (6250 tiles total)
    int m0 = tile * 16;
    if (m0 >= N_NODES) return;           // tail waves idle (no further barriers)

    int lrow = lane & 15;                // m-within-tile for A; col for C/D
    int quad = lane >> 4;

    // A fragments: lane holds A[m=lrow][k = kc*32 + quad*8 + j], j=0..7
    int gm_a = m0 + lrow;
    const float* xrow = x + (long)gm_a * C;
    short8 afrag[4];
#pragma unroll
    for (int kc = 0; kc < 4; ++kc) {
        int k0 = kc * 32 + quad * 8;
        f32x4 x0 = *reinterpret_cast<const f32x4*>(xrow + k0);
        f32x4 x1 = *reinterpret_cast<const f32x4*>(xrow + k0 + 4);
        short8 a;
        a[0] = (short)f2bf(x0[0]); a[1] = (short)f2bf(x0[1]);
        a[2] = (short)f2bf(x0[2]); a[3] = (short)f2bf(x0[3]);
        a[4] = (short)f2bf(x1[0]); a[5] = (short)f2bf(x1[1]);
        a[6] = (short)f2bf(x1[2]); a[7] = (short)f2bf(x1[3]);
        afrag[kc] = a;
    }

    // out_norm for the 4 rows this lane will write (D rows = quad*4 + r)
    float onorm[4];
#pragma unroll
    for (int r = 0; r < 4; ++r) {
        int gm = m0 + quad * 4 + r;
        onorm[r] = rsqrtf((float)(colptr[gm + 1] - colptr[gm]));
    }

#pragma unroll
    for (int nt = 0; nt < 8; ++nt) {
        f32x4 acc = {0.f, 0.f, 0.f, 0.f};
        int n = nt * 16 + lrow;          // B col this lane supplies
#pragma unroll
        for (int kc = 0; kc < 4; ++kc) {
            int k0 = kc * 32 + quad * 8;
            short8 b = *reinterpret_cast<const short8*>(&wt[n * LDS_STRIDE + k0]);
            acc = __builtin_amdgcn_mfma_f32_16x16x32_bf16(afrag[kc], b, acc, 0, 0, 0);
        }
        // D layout: col = lane&15, row = quad*4 + reg  (guide §3, m89-verified)
#pragma unroll
        for (int r = 0; r < 4; ++r) {
            int gm = m0 + quad * 4 + r;
            h[(long)gm * C + nt * 16 + lrow] = f2bf(acc[r] * onorm[r]);
        }
    }
}

// ---------------------------------------------------------------------------
// Kernel 2: out[i][c] = in_norm[i] * sum_{e in row i} h_bf16[colind[e]][c] + bias[c]
// One wave per node. lane = (edge_group: lane>>4) x (col_group: lane&15, 8 cols).
// ---------------------------------------------------------------------------
__global__ __launch_bounds__(256, 8)
void gcn_aggr_kernel(const unsigned short* __restrict__ h,
                     const int* __restrict__ rowptr,
                     const int* __restrict__ colind,
                     const float* __restrict__ bias,
                     float* __restrict__ out)
{
    int tid = threadIdx.x;
    int wave = tid >> 6;
    int lane = tid & 63;
    int node = blockIdx.x * 4 + wave;    // grid is exactly 25000*4 = 100000

    int cg = lane & 15;                  // column group: cols cg*8 .. cg*8+7
    int eg = lane >> 4;                  // edge group 0..3

    int base = rowptr[node];
    int deg  = rowptr[node + 1] - base;
    float innorm = rsqrtf((float)deg);

    // lanes use (lane&15) so lanes 0..15 hold colind[base+0..15]; deg==16 fixed
    int myidx = colind[base + cg];

    float acc[8];
#pragma unroll
    for (int i = 0; i < 8; ++i) acc[i] = 0.f;

#pragma unroll
    for (int it = 0; it < 4; ++it) {
        int e = it * 4 + eg;
        int j = __shfl(myidx, e);
        const unsigned short* row = h + (long)j * C + cg * 8;
        int4 v = *reinterpret_cast<const int4*>(row);   // 8 bf16 = 16 B
        unsigned int p0 = (unsigned int)v.x;
        unsigned int p1 = (unsigned int)v.y;
        unsigned int p2 = (unsigned int)v.z;
        unsigned int p3 = (unsigned int)v.w;
        acc[0] += bflo(p0); acc[1] += bfhi(p0);
        acc[2] += bflo(p1); acc[3] += bfhi(p1);
        acc[4] += bflo(p2); acc[5] += bfhi(p2);
        acc[6] += bflo(p3); acc[7] += bfhi(p3);
    }

    // reduce over the 4 edge groups (lanes cg, cg+16, cg+32, cg+48)
#pragma unroll
    for (int i = 0; i < 8; ++i) {
        acc[i] += __shfl_xor(acc[i], 16);
        acc[i] += __shfl_xor(acc[i], 32);
    }

    if (eg == 0) {
        const f32x4* bp = reinterpret_cast<const f32x4*>(bias + cg * 8);
        f32x4 b0 = bp[0], b1 = bp[1];
        f32x4 o0, o1;
        o0[0] = acc[0] * innorm + b0[0];
        o0[1] = acc[1] * innorm + b0[1];
        o0[2] = acc[2] * innorm + b0[2];
        o0[3] = acc[3] * innorm + b0[3];
        o1[0] = acc[4] * innorm + b1[0];
        o1[1] = acc[5] * innorm + b1[1];
        o1[2] = acc[6] * innorm + b1[2];
        o1[3] = acc[7] * innorm + b1[3];
        float* op = out + (long)node * C + cg * 8;
        *reinterpret_cast<f32x4*>(op)     = o0;
        *reinterpret_cast<f32x4*>(op + 4) = o1;
    }
}

extern "C" void kernel_launch(void* const* d_in, const int* in_sizes, int n_in,
                              void* d_out, int out_size, void* d_ws, size_t ws_size,
                              hipStream_t stream) {
    const float* x      = (const float*)d_in[0];
    const float* w      = (const float*)d_in[1];
    const float* bias   = (const float*)d_in[2];
    const int*   rowptr = (const int*)d_in[3];
    const int*   colind = (const int*)d_in[4];
    const int*   colptr = (const int*)d_in[5];
    // d_in[6] = rowind (unused by the reference math)
    float* out = (float*)d_out;
    unsigned short* h = (unsigned short*)d_ws;   // bf16 h, 100000*128*2 = 25.6 MB

    // 6250 wave-tiles of 16 rows, 4 waves/block -> 1563 blocks (last 2 waves idle)
    gcn_gemm_kernel<<<1563, 256, 0, stream>>>(x, w, colptr, h);
    // one wave per node, 4 waves/block -> exactly 25000 blocks
    gcn_aggr_kernel<<<25000, 256, 0, stream>>>(h, rowptr, colind, bias, out);
}

// Round 2
// 174.628 us; speedup vs baseline: 1.0071x; 1.0071x over previous
//
#include <hip/hip_runtime.h>
#include <hip/hip_bf16.h>

#define N_NODES 100000
#define DEG 16
#define C 128            // C_IN == C_OUT == 128
#define NTILES 6250      // 100000 / 16
#define GEMM_BLOCKS 256
#define GEMM_WAVES 8     // 512 threads/block

typedef __attribute__((ext_vector_type(8))) short short8;
typedef __attribute__((ext_vector_type(4))) float f32x4;

// fp32 -> bf16 bits, round-to-nearest-even (matches numpy)
__device__ inline unsigned short f2bf(float f) {
    unsigned int u = __builtin_bit_cast(unsigned int, f);
    u += 0x7fffu + ((u >> 16) & 1u);
    return (unsigned short)(u >> 16);
}
__device__ inline float bflo(unsigned int p) { return __builtin_bit_cast(float, p << 16); }
__device__ inline float bfhi(unsigned int p) { return __builtin_bit_cast(float, p & 0xffff0000u); }

// ---------------------------------------------------------------------------
// Kernel 1: h[m][n] = (sum_k x[m][k] * W[k][n]) * out_norm[m], stored bf16.
// W staged ONCE per block into LDS in MFMA-fragment-linear order (16B chunk
// per lane per frag -> conflict-free b128 reads), then all 32 B-fragments
// hoisted to registers (128 VGPR) -- zero LDS traffic in the tile loop.
// Grid-stride over 16-row tiles with software-pipelined A prefetch.
// ---------------------------------------------------------------------------
__global__ __launch_bounds__(512, 2)
void gcn_gemm_kernel(const float* __restrict__ x, const float* __restrict__ w,
                     const int* __restrict__ colptr, unsigned short* __restrict__ h)
{
    __shared__ unsigned short wfrag[32 * 64 * 8];   // 32 KB, frag-linear

    int tid = threadIdx.x;
    // coalesced read of W (row-major [k][n]); scatter-write into frag order
    for (int i = tid; i < C * C; i += 512) {
        int k = i >> 7, n = i & 127;
        int nt = n >> 4, lr = n & 15;
        int kc = k >> 5, quad = (k >> 3) & 3, j = k & 7;
        wfrag[((((nt << 2) + kc) << 6) + (quad << 4) + lr) * 8 + j] = f2bf(w[i]);
    }
    __syncthreads();

    int wave = tid >> 6;
    int lane = tid & 63;
    int lrow = lane & 15;
    int quad = lane >> 4;

    // hoist all B fragments: frag (nt,kc), lane L reads its own 16B chunk
    short8 bf[8][4];
#pragma unroll
    for (int nt = 0; nt < 8; ++nt)
#pragma unroll
        for (int kc = 0; kc < 4; ++kc)
            bf[nt][kc] = *reinterpret_cast<const short8*>(
                &wfrag[((((nt << 2) + kc) << 6) + lane) * 8]);

    int tile = blockIdx.x * GEMM_WAVES + wave;
    if (tile >= NTILES) return;
    const int tstride = GEMM_BLOCKS * GEMM_WAVES;   // 2048

    // prefetch first A tile: lane holds x[m0+lrow][quad*8 + kc*32 .. +8]
    f32x4 xb[8];
    {
        const float* xr = x + (long)(tile * 16 + lrow) * C + quad * 8;
#pragma unroll
        for (int kc = 0; kc < 4; ++kc) {
            xb[2*kc]   = *reinterpret_cast<const f32x4*>(xr + kc * 32);
            xb[2*kc+1] = *reinterpret_cast<const f32x4*>(xr + kc * 32 + 4);
        }
    }

    while (true) {
        int m0 = tile * 16;
        short8 af[4];
#pragma unroll
        for (int kc = 0; kc < 4; ++kc) {
            short8 a;
            a[0] = (short)f2bf(xb[2*kc][0]);   a[1] = (short)f2bf(xb[2*kc][1]);
            a[2] = (short)f2bf(xb[2*kc][2]);   a[3] = (short)f2bf(xb[2*kc][3]);
            a[4] = (short)f2bf(xb[2*kc+1][0]); a[5] = (short)f2bf(xb[2*kc+1][1]);
            a[6] = (short)f2bf(xb[2*kc+1][2]); a[7] = (short)f2bf(xb[2*kc+1][3]);
            af[kc] = a;
        }
        float onorm[4];
#pragma unroll
        for (int r = 0; r < 4; ++r) {
            int gm = m0 + quad * 4 + r;
            onorm[r] = rsqrtf((float)(colptr[gm + 1] - colptr[gm]));
        }

        int next = tile + tstride;
        bool more = next < NTILES;
        if (more) {   // prefetch next A tile before the MFMA burst
            const float* xr = x + (long)(next * 16 + lrow) * C + quad * 8;
#pragma unroll
            for (int kc = 0; kc < 4; ++kc) {
                xb[2*kc]   = *reinterpret_cast<const f32x4*>(xr + kc * 32);
                xb[2*kc+1] = *reinterpret_cast<const f32x4*>(xr + kc * 32 + 4);
            }
        }

#pragma unroll
        for (int nt = 0; nt < 8; ++nt) {
            f32x4 acc = {0.f, 0.f, 0.f, 0.f};
#pragma unroll
            for (int kc = 0; kc < 4; ++kc)
                acc = __builtin_amdgcn_mfma_f32_16x16x32_bf16(af[kc], bf[nt][kc], acc, 0, 0, 0);
            // D layout: col = lane&15, row = quad*4 + reg (m89-verified)
            unsigned short* hp = h + (long)(m0 + quad * 4) * C + nt * 16 + lrow;
#pragma unroll
            for (int r = 0; r < 4; ++r)
                hp[r * C] = f2bf(acc[r] * onorm[r]);
        }
        if (!more) break;
        tile = next;
    }
}

// ---------------------------------------------------------------------------
// Kernel 2: out[i][c] = in_norm[i] * sum_e h_bf16[colind[e]][c] + bias[c]
// TWO nodes per wave; all 8 dwordx4 gathers issued before any accumulation
// (2x memory-level parallelism vs round 1).
// ---------------------------------------------------------------------------
__global__ __launch_bounds__(256, 6)
void gcn_aggr_kernel(const unsigned short* __restrict__ h,
                     const int* __restrict__ rowptr,
                     const int* __restrict__ colind,
                     const float* __restrict__ bias,
                     float* __restrict__ out)
{
    int tid = threadIdx.x;
    int wave = tid >> 6;
    int lane = tid & 63;
    int node0 = (blockIdx.x * 4 + wave) * 2;   // grid 12500 -> nodes 0..99999
    int node1 = node0 + 1;

    int cg = lane & 15;      // column group: cols cg*8 .. cg*8+7
    int eg = lane >> 4;      // edge group 0..3

    int base0 = rowptr[node0];
    int deg0  = rowptr[node0 + 1] - base0;
    int base1 = rowptr[node1];
    int deg1  = rowptr[node1 + 1] - base1;
    float innorm0 = rsqrtf((float)deg0);
    float innorm1 = rsqrtf((float)deg1);

    int myidx0 = colind[base0 + cg];   // lanes 0..15 hold the 16 edges
    int myidx1 = colind[base1 + cg];

    int4 v0[4], v1[4];
#pragma unroll
    for (int it = 0; it < 4; ++it) {
        int e = it * 4 + eg;
        int j0 = __shfl(myidx0, e);
        int j1 = __shfl(myidx1, e);
        v0[it] = *reinterpret_cast<const int4*>(h + (long)j0 * C + cg * 8);
        v1[it] = *reinterpret_cast<const int4*>(h + (long)j1 * C + cg * 8);
    }

    float acc0[8], acc1[8];
#pragma unroll
    for (int i = 0; i < 8; ++i) { acc0[i] = 0.f; acc1[i] = 0.f; }

#pragma unroll
    for (int it = 0; it < 4; ++it) {
        unsigned int p;
        p = (unsigned int)v0[it].x; acc0[0] += bflo(p); acc0[1] += bfhi(p);
        p = (unsigned int)v0[it].y; acc0[2] += bflo(p); acc0[3] += bfhi(p);
        p = (unsigned int)v0[it].z; acc0[4] += bflo(p); acc0[5] += bfhi(p);
        p = (unsigned int)v0[it].w; acc0[6] += bflo(p); acc0[7] += bfhi(p);
        p = (unsigned int)v1[it].x; acc1[0] += bflo(p); acc1[1] += bfhi(p);
        p = (unsigned int)v1[it].y; acc1[2] += bflo(p); acc1[3] += bfhi(p);
        p = (unsigned int)v1[it].z; acc1[4] += bflo(p); acc1[5] += bfhi(p);
        p = (unsigned int)v1[it].w; acc1[6] += bflo(p); acc1[7] += bfhi(p);
    }

    // reduce over the 4 edge groups (lanes cg, cg+16, cg+32, cg+48)
#pragma unroll
    for (int i = 0; i < 8; ++i) {
        acc0[i] += __shfl_xor(acc0[i], 16);
        acc0[i] += __shfl_xor(acc0[i], 32);
        acc1[i] += __shfl_xor(acc1[i], 16);
        acc1[i] += __shfl_xor(acc1[i], 32);
    }

    if (eg < 2) {
        float inn = (eg == 0) ? innorm0 : innorm1;
        int   nd  = (eg == 0) ? node0 : node1;
        float* a  = (eg == 0) ? acc0 : acc1;
        const f32x4* bp = reinterpret_cast<const f32x4*>(bias + cg * 8);
        f32x4 b0 = bp[0], b1 = bp[1];
        f32x4 o0, o1;
        o0[0] = a[0] * inn + b0[0];
        o0[1] = a[1] * inn + b0[1];
        o0[2] = a[2] * inn + b0[2];
        o0[3] = a[3] * inn + b0[3];
        o1[0] = a[4] * inn + b1[0];
        o1[1] = a[5] * inn + b1[1];
        o1[2] = a[6] * inn + b1[2];
        o1[3] = a[7] * inn + b1[3];
        float* op = out + (long)nd * C + cg * 8;
        *reinterpret_cast<f32x4*>(op)     = o0;
        *reinterpret_cast<f32x4*>(op + 4) = o1;
    }
}

extern "C" void kernel_launch(void* const* d_in, const int* in_sizes, int n_in,
                              void* d_out, int out_size, void* d_ws, size_t ws_size,
                              hipStream_t stream) {
    const float* x      = (const float*)d_in[0];
    const float* w      = (const float*)d_in[1];
    const float* bias   = (const float*)d_in[2];
    const int*   rowptr = (const int*)d_in[3];
    const int*   colind = (const int*)d_in[4];
    const int*   colptr = (const int*)d_in[5];
    // d_in[6] = rowind (unused by the reference math)
    float* out = (float*)d_out;
    unsigned short* h = (unsigned short*)d_ws;   // bf16 h, 100000*128*2 = 25.6 MB

    gcn_gemm_kernel<<<GEMM_BLOCKS, 512, 0, stream>>>(x, w, colptr, h);
    // two nodes per wave, 4 waves/block -> 12500 blocks covers 100000 nodes
    gcn_aggr_kernel<<<12500, 256, 0, stream>>>(h, rowptr, colind, bias, out);
}